// Round 5
// baseline (1405.767 us; speedup 1.0000x reference)
//
#include <hip/hip_runtime.h>
#include <hip/hip_fp16.h>

#define B_ 256
#define T_ 512
#define I_ 156
#define H_ 128
#define L_ 32
#define G_ 512  // 4*H

typedef _Float16 half_t;
typedef _Float16 h2_t __attribute__((ext_vector_type(2)));

union U8 { uint4 u; h2_t h2[4]; };

__device__ __forceinline__ float fdot2(h2_t a, h2_t b, float c) {
#if __has_builtin(__builtin_amdgcn_fdot2)
  return __builtin_amdgcn_fdot2(a, b, c, false);
#else
  return c + (float)a[0] * (float)b[0] + (float)a[1] * (float)b[1];
#endif
}

__device__ __forceinline__ h2_t pk2(float a, float b) {
  h2_t r; r[0] = (half_t)a; r[1] = (half_t)b; return r;
}

__device__ __forceinline__ float sigf(float x) { return 1.0f / (1.0f + __expf(-x)); }
__device__ __forceinline__ float tanhf_(float x) {
  x = fminf(fmaxf(x, -20.f), 20.f);
  float e = __expf(2.f * x);
  return (e - 1.f) / (e + 1.f);
}

// =================== xproj: XP[B*T,512] = motion x Wih^T + b (f16) ==========
// 2048 blocks x 1024 thr; each block 64 rows in 8 chunks of 8.
// K split 2-way: thread (kpart, j) holds 40 h2 of Wih row j -> fits 64 VGPRs.
__global__ __launch_bounds__(1024) void xproj_kernel(
    const float* __restrict__ motion, const float* __restrict__ Wih,
    const float* __restrict__ bv, half_t* __restrict__ XP)
{
  const int tid = threadIdx.x;
  const int kpart = tid >> 9;
  const int j = tid & 511;

  __shared__ h2_t xb[8][80];            // 8 rows x 160 f16 (padded)
  __shared__ float pp[8][512][2];       // partial sums

  h2_t wih[40];
  {
    const float* wr = Wih + (size_t)j * I_;
#pragma unroll
    for (int k = 0; k < 40; ++k) {
      int c0 = kpart * 80 + 2 * k;
      float a = (c0     < I_) ? wr[c0]     : 0.f;
      float c = (c0 + 1 < I_) ? wr[c0 + 1] : 0.f;
      wih[k] = pk2(a, c);
    }
  }
  const float bj = (kpart == 0) ? bv[j] : 0.f;

  const float2* mf2 = (const float2*)motion;
  const int blk = blockIdx.x;

  for (int c = 0; c < 8; ++c) {
    const int rowbase = blk * 64 + c * 8;
    // stage 8 rows of motion into LDS as f16
    if (tid < 624) {
      int r = tid / 78, e = tid % 78;
      float2 m = mf2[(size_t)(rowbase + r) * 78 + e];
      xb[r][e] = pk2(m.x, m.y);
    } else if (tid < 640) {
      int r = tid - 624;
      xb[r][78] = pk2(0.f, 0.f); xb[r][79] = pk2(0.f, 0.f);
    }
    __syncthreads();
#pragma unroll
    for (int r = 0; r < 8; ++r) {
      float a0 = bj, a1 = 0.f;
      const U8* xv = (const U8*)&xb[r][kpart * 40];
#pragma unroll
      for (int q = 0; q < 5; ++q) {
        U8 v0 = xv[2*q], v1 = xv[2*q+1];
        a0 = fdot2(wih[8*q+0], v0.h2[0], a0);
        a1 = fdot2(wih[8*q+1], v0.h2[1], a1);
        a0 = fdot2(wih[8*q+2], v0.h2[2], a0);
        a1 = fdot2(wih[8*q+3], v0.h2[3], a1);
        a0 = fdot2(wih[8*q+4], v1.h2[0], a0);
        a1 = fdot2(wih[8*q+5], v1.h2[1], a1);
        a0 = fdot2(wih[8*q+6], v1.h2[2], a0);
        a1 = fdot2(wih[8*q+7], v1.h2[3], a1);
      }
      pp[r][j][kpart] = a0 + a1;
    }
    __syncthreads();
#pragma unroll
    for (int k = 0; k < 4; ++k) {
      int idx = tid + k * 1024;
      int r = idx >> 9, jj = idx & 511;
      XP[(size_t)(rowbase + r) * 512 + jj] = (half_t)(pp[r][jj][0] + pp[r][jj][1]);
    }
    __syncthreads();
  }
}

// =================== encoder recurrence (XP precomputed) ====================
// 256 blocks x 1024 thr. Thread (part,j): 32 h2 of Whh row j. ~50 VGPRs.
__global__ __launch_bounds__(1024) void enc_rec_kernel(
    const half_t* __restrict__ XP, const float* __restrict__ eps,
    const float* __restrict__ Whh,
    const float* __restrict__ muW, const float* __restrict__ mub,
    const float* __restrict__ varW, const float* __restrict__ varb,
    const float* __restrict__ fcW, const float* __restrict__ fcb,
    float* __restrict__ dout, float* __restrict__ dh0,
    float* __restrict__ accums)
{
  const int tid  = threadIdx.x;
  const int part = tid >> 9;
  const int j    = tid & 511;
  const int b    = blockIdx.x;

  __shared__ h2_t hs[64];
  __shared__ float gl2[2][G_];
  __shared__ float hf[H_];
  __shared__ float mulv[64];
  __shared__ float zs[L_];

  h2_t whh[32];
  {
    const float2* r2 = (const float2*)Whh;
#pragma unroll
    for (int k = 0; k < 32; ++k) {
      float2 w = r2[(size_t)j * 64 + part * 32 + k];
      whh[k] = pk2(w.x, w.y);
    }
  }

  float creg = 0.f, hreg = 0.f;
  if (tid < 64) hs[tid] = pk2(0.f, 0.f);
  __syncthreads();

  const half_t* xpb = XP + (size_t)b * 512 * 512 + j;
  half_t xpc = (half_t)0.f, xpn = (half_t)0.f;
  if (part == 0) xpc = xpb[0];

  for (int t = 0; t < T_; ++t) {
    if (part == 0 && t + 1 < T_) xpn = xpb[(size_t)(t + 1) * 512];

    float a0 = (part == 0) ? (float)xpc : 0.f;
    float a1 = 0.f;
    const U8* hv = (const U8*)&hs[part * 32];
#pragma unroll
    for (int q = 0; q < 4; ++q) {
      U8 v0 = hv[2*q], v1 = hv[2*q+1];
      a0 = fdot2(whh[8*q+0], v0.h2[0], a0);
      a1 = fdot2(whh[8*q+1], v0.h2[1], a1);
      a0 = fdot2(whh[8*q+2], v0.h2[2], a0);
      a1 = fdot2(whh[8*q+3], v0.h2[3], a1);
      a0 = fdot2(whh[8*q+4], v1.h2[0], a0);
      a1 = fdot2(whh[8*q+5], v1.h2[1], a1);
      a0 = fdot2(whh[8*q+6], v1.h2[2], a0);
      a1 = fdot2(whh[8*q+7], v1.h2[3], a1);
    }
    gl2[part][j] = a0 + a1;
    __syncthreads();

    if (tid < H_) {
      float ig = gl2[0][tid]        + gl2[1][tid];
      float fg = gl2[0][tid +   H_] + gl2[1][tid +   H_];
      float gg = gl2[0][tid + 2*H_] + gl2[1][tid + 2*H_];
      float og = gl2[0][tid + 3*H_] + gl2[1][tid + 3*H_];
      creg = sigf(fg) * creg + sigf(ig) * tanhf_(gg);
      hreg = sigf(og) * tanhf_(creg);
      ((half_t*)hs)[tid] = (half_t)hreg;
    }
    __syncthreads();
    xpc = xpn;
  }

  // ---- tail: mu/logvar, z, KL, dh0 ----
  if (tid < H_) hf[tid] = hreg;
  __syncthreads();

  if (tid < 64) {
    const float* wr = (tid < L_) ? (muW + tid * H_) : (varW + (tid - L_) * H_);
    float a = (tid < L_) ? mub[tid] : varb[tid - L_];
#pragma unroll 8
    for (int k = 0; k < H_; ++k) a += wr[k] * hf[k];
    mulv[tid] = a;
    if (tid < L_) dout[(size_t)B_*T_*I_ + b * L_ + tid] = a;
    else          dout[(size_t)B_*T_*I_ + B_*L_ + b * L_ + (tid - L_)] = a;
  }
  __syncthreads();

  if (tid < L_) {
    float mu = mulv[tid], lv = mulv[tid + L_];
    float z = mu + eps[b * L_ + tid] * __expf(0.5f * lv);
    zs[tid] = z;
    float kt = 1.f + lv - mu * mu - __expf(lv);
#pragma unroll
    for (int off = 16; off > 0; off >>= 1) kt += __shfl_down(kt, off, 64);
    if (tid == 0) atomicAdd(&accums[1], kt);
  }
  __syncthreads();

  if (tid < H_) {
    const float* wr = fcW + tid * L_;
    float a = fcb[tid];
#pragma unroll
    for (int l = 0; l < L_; ++l) a += wr[l] * zs[l];
    dh0[b * H_ + tid] = a;
  }
}

// ============ fallback encoder (R2 structure, weights may spill) ============
__global__ __launch_bounds__(1024) void enc_fb_kernel(
    const float* __restrict__ motion, const float* __restrict__ eps,
    const float* __restrict__ Wih, const float* __restrict__ Whh,
    const float* __restrict__ bv,
    const float* __restrict__ muW, const float* __restrict__ mub,
    const float* __restrict__ varW, const float* __restrict__ varb,
    const float* __restrict__ fcW, const float* __restrict__ fcb,
    float* __restrict__ dout, float* __restrict__ dh0,
    float* __restrict__ accums)
{
  const int tid  = threadIdx.x;
  const int part = tid >> 9;
  const int j    = tid & 511;
  const int b    = blockIdx.x;

  __shared__ h2_t xs[2][80];
  __shared__ h2_t hs[64];
  __shared__ float gl2[2][G_];
  __shared__ float hf[H_];
  __shared__ float mulv[64];
  __shared__ float zs[L_];

  h2_t wih[40];
  h2_t whh[32];
  {
    const int cbase = part * 80;
    const float* wr = Wih + (size_t)j * I_;
#pragma unroll
    for (int k = 0; k < 40; ++k) {
      int c0 = cbase + 2 * k;
      float a = (c0     < I_) ? wr[c0]     : 0.f;
      float c = (c0 + 1 < I_) ? wr[c0 + 1] : 0.f;
      wih[k] = pk2(a, c);
    }
    const float2* r2 = (const float2*)(Whh + (size_t)j * H_ + part * 64);
#pragma unroll
    for (int k = 0; k < 32; ++k) { float2 w = r2[k]; whh[k] = pk2(w.x, w.y); }
  }

  float cb0 = 0.f, cb1 = 0.f, cb2 = 0.f, cb3 = 0.f;
  if (tid < H_) {
    cb0 = bv[tid]; cb1 = bv[tid + H_]; cb2 = bv[tid + 2*H_]; cb3 = bv[tid + 3*H_];
  }

  float creg = 0.f, hreg = 0.f;
  if (tid < 64) hs[tid] = pk2(0.f, 0.f);
  if (tid < 4)  xs[tid >> 1][78 + (tid & 1)] = pk2(0.f, 0.f);

  const float2* mrow = (const float2*)(motion + (size_t)b * T_ * I_);
  const bool loader = (part == 1) && (j < 78);
  if (loader) { float2 m = mrow[j]; xs[0][j] = pk2(m.x, m.y); }
  __syncthreads();

  int cur = 0;
  float2 xreg;
  for (int t = 0; t < T_; ++t) {
    if (loader && t + 1 < T_) xreg = mrow[(t + 1) * 78 + j];

    float a0 = 0.f, a1 = 0.f, a2 = 0.f, a3 = 0.f;
    const U8* xv = (const U8*)&xs[cur][part * 40];
#pragma unroll
    for (int c = 0; c < 10; ++c) {
      U8 v = xv[c];
      a0 = fdot2(wih[4*c+0], v.h2[0], a0);
      a1 = fdot2(wih[4*c+1], v.h2[1], a1);
      a2 = fdot2(wih[4*c+2], v.h2[2], a2);
      a3 = fdot2(wih[4*c+3], v.h2[3], a3);
    }
    const U8* hv = (const U8*)&hs[part * 32];
#pragma unroll
    for (int c = 0; c < 8; ++c) {
      U8 v = hv[c];
      a0 = fdot2(whh[4*c+0], v.h2[0], a0);
      a1 = fdot2(whh[4*c+1], v.h2[1], a1);
      a2 = fdot2(whh[4*c+2], v.h2[2], a2);
      a3 = fdot2(whh[4*c+3], v.h2[3], a3);
    }
    gl2[part][j] = (a0 + a1) + (a2 + a3);
    if (loader && t + 1 < T_) xs[cur ^ 1][j] = pk2(xreg.x, xreg.y);
    __syncthreads();

    if (tid < H_) {
      float ig = gl2[0][tid]        + gl2[1][tid]        + cb0;
      float fg = gl2[0][tid +   H_] + gl2[1][tid +   H_] + cb1;
      float gg = gl2[0][tid + 2*H_] + gl2[1][tid + 2*H_] + cb2;
      float og = gl2[0][tid + 3*H_] + gl2[1][tid + 3*H_] + cb3;
      creg = sigf(fg) * creg + sigf(ig) * tanhf_(gg);
      hreg = sigf(og) * tanhf_(creg);
      ((half_t*)hs)[tid] = (half_t)hreg;
    }
    __syncthreads();
    cur ^= 1;
  }

  if (tid < H_) hf[tid] = hreg;
  __syncthreads();

  if (tid < 64) {
    const float* wr = (tid < L_) ? (muW + tid * H_) : (varW + (tid - L_) * H_);
    float a = (tid < L_) ? mub[tid] : varb[tid - L_];
#pragma unroll 8
    for (int k = 0; k < H_; ++k) a += wr[k] * hf[k];
    mulv[tid] = a;
    if (tid < L_) dout[(size_t)B_*T_*I_ + b * L_ + tid] = a;
    else          dout[(size_t)B_*T_*I_ + B_*L_ + b * L_ + (tid - L_)] = a;
  }
  __syncthreads();

  if (tid < L_) {
    float mu = mulv[tid], lv = mulv[tid + L_];
    float z = mu + eps[b * L_ + tid] * __expf(0.5f * lv);
    zs[tid] = z;
    float kt = 1.f + lv - mu * mu - __expf(lv);
#pragma unroll
    for (int off = 16; off > 0; off >>= 1) kt += __shfl_down(kt, off, 64);
    if (tid == 0) atomicAdd(&accums[1], kt);
  }
  __syncthreads();

  if (tid < H_) {
    const float* wr = fcW + tid * L_;
    float a = fcb[tid];
#pragma unroll
    for (int l = 0; l < L_; ++l) a += wr[l] * zs[l];
    dh0[b * H_ + tid] = a;
  }
}

// =================== decoder: recurrence + 4-way-split proj =================
// All 1024 threads: gate half-rows (32 h2). Threads 0..623: proj partials
// (16 h2, K/4 each) into pp LDS. Threads 624..779: deferred finalize of the
// previous step's partials (recon[t-2] + loss). ~58 VGPRs -> no/low spill.
__global__ __launch_bounds__(1024) void dec_kernel(
    const float* __restrict__ motion,
    const float* __restrict__ Wih, const float* __restrict__ Whh,
    const float* __restrict__ bv,
    const float* __restrict__ oW, const float* __restrict__ ob,
    const float* __restrict__ dh0,
    float* __restrict__ dout, float* __restrict__ accums)
{
  const int tid  = threadIdx.x;
  const int part = tid >> 9;
  const int j    = tid & 511;
  const int b    = blockIdx.x;

  __shared__ h2_t hs[64];
  __shared__ float gl2[2][G_];
  __shared__ float pp[2][156][4];
  __shared__ float red[16];

  h2_t wd[32];
  {
    const float2* r1 = (const float2*)Wih;
    const float2* r2 = (const float2*)Whh;
#pragma unroll
    for (int k = 0; k < 32; ++k) {
      float2 a = r1[(size_t)j * 64 + part * 32 + k];
      float2 c = r2[(size_t)j * 64 + part * 32 + k];
      wd[k] = pk2(a.x + c.x, a.y + c.y);
    }
  }
  const float breg = (part == 0) ? bv[j] : 0.f;

  const bool isproj = tid < 624;
  const int pcol = isproj ? (tid % 156) : 0;
  const int pk   = isproj ? (tid / 156) : 0;
  h2_t wo[16];
  float obreg = 0.f;
  if (isproj) {
    const float2* r = (const float2*)oW;
#pragma unroll
    for (int k = 0; k < 16; ++k) {
      float2 w = r[(size_t)pcol * 64 + pk * 16 + k];
      wo[k] = pk2(w.x, w.y);
    }
    if (pk == 0) obreg = ob[pcol];
  }
  const bool isfin = (tid >= 624) && (tid < 780);
  const int fcol = isfin ? (tid - 624) : 0;

  float creg = 0.f, hreg = 0.f;
  if (tid < H_) {
    hreg = dh0[b * H_ + tid];
    ((half_t*)hs)[tid] = (half_t)hreg;
  }
  __syncthreads();

  const float* mr = motion + (size_t)b * T_ * I_;
  float* rr = dout + (size_t)b * T_ * I_;
  float rl = 0.f;

  for (int t = 0; t < T_; ++t) {
    // ---- phase A: gates(h_t) + proj-partials(h_t) + finalize(h_{t-1}) ----
    {
      float a0 = breg, a1 = 0.f;
      const U8* hv = (const U8*)&hs[part * 32];
#pragma unroll
      for (int q = 0; q < 4; ++q) {
        U8 v0 = hv[2*q], v1 = hv[2*q+1];
        a0 = fdot2(wd[8*q+0], v0.h2[0], a0);
        a1 = fdot2(wd[8*q+1], v0.h2[1], a1);
        a0 = fdot2(wd[8*q+2], v0.h2[2], a0);
        a1 = fdot2(wd[8*q+3], v0.h2[3], a1);
        a0 = fdot2(wd[8*q+4], v1.h2[0], a0);
        a1 = fdot2(wd[8*q+5], v1.h2[1], a1);
        a0 = fdot2(wd[8*q+6], v1.h2[2], a0);
        a1 = fdot2(wd[8*q+7], v1.h2[3], a1);
      }
      gl2[part][j] = a0 + a1;
    }
    if (isproj) {
      float pa = obreg;
      const U8* hv = (const U8*)&hs[pk * 16];
#pragma unroll
      for (int q = 0; q < 4; ++q) {
        U8 v = hv[q];
        pa = fdot2(wo[4*q+0], v.h2[0], pa);
        pa = fdot2(wo[4*q+1], v.h2[1], pa);
        pa = fdot2(wo[4*q+2], v.h2[2], pa);
        pa = fdot2(wo[4*q+3], v.h2[3], pa);
      }
      pp[t & 1][pcol][pk] = pa;
    }
    if (isfin && t >= 2) {
      int par = (t - 1) & 1;
      float v = pp[par][fcol][0] + pp[par][fcol][1] + pp[par][fcol][2] + pp[par][fcol][3];
      rr[(size_t)(t - 2) * I_ + fcol] = v;
      float d = v - mr[(size_t)(t - 2) * I_ + fcol];
      rl += d * d;
    }
    __syncthreads();

    if (tid < H_) {
      float ig = gl2[0][tid]        + gl2[1][tid];
      float fg = gl2[0][tid +   H_] + gl2[1][tid +   H_];
      float gg = gl2[0][tid + 2*H_] + gl2[1][tid + 2*H_];
      float og = gl2[0][tid + 3*H_] + gl2[1][tid + 3*H_];
      creg = sigf(fg) * creg + sigf(ig) * tanhf_(gg);
      hreg = sigf(og) * tanhf_(creg);
      ((half_t*)hs)[tid] = (half_t)hreg;
    }
    __syncthreads();
  }

  // ---- epilogue: pp(h_512) + finalize recon[510], recon[511] ----
  if (isproj) {
    float pa = obreg;
    const U8* hv = (const U8*)&hs[pk * 16];
#pragma unroll
    for (int q = 0; q < 4; ++q) {
      U8 v = hv[q];
      pa = fdot2(wo[4*q+0], v.h2[0], pa);
      pa = fdot2(wo[4*q+1], v.h2[1], pa);
      pa = fdot2(wo[4*q+2], v.h2[2], pa);
      pa = fdot2(wo[4*q+3], v.h2[3], pa);
    }
    pp[0][pcol][pk] = pa;   // parity of t=512 is 0
  }
  if (isfin) {  // h_511 partials are at parity 511&1 == 1
    float v = pp[1][fcol][0] + pp[1][fcol][1] + pp[1][fcol][2] + pp[1][fcol][3];
    rr[(size_t)510 * I_ + fcol] = v;
    float d = v - mr[(size_t)510 * I_ + fcol];
    rl += d * d;
  }
  __syncthreads();
  if (isfin) {
    float v = pp[0][fcol][0] + pp[0][fcol][1] + pp[0][fcol][2] + pp[0][fcol][3];
    rr[(size_t)511 * I_ + fcol] = v;
    float d = v - mr[(size_t)511 * I_ + fcol];
    rl += d * d;
  }

  // block reduction of squared error
  float v = rl;
#pragma unroll
  for (int off = 32; off > 0; off >>= 1) v += __shfl_down(v, off, 64);
  if ((tid & 63) == 0) red[tid >> 6] = v;
  __syncthreads();
  if (tid == 0) {
    float s = 0.f;
#pragma unroll
    for (int w = 0; w < 16; ++w) s += red[w];
    atomicAdd(&accums[0], s);
  }
}

__global__ void init_kernel(float* accums) {
  if (threadIdx.x < 2) accums[threadIdx.x] = 0.f;
}

__global__ void fin_kernel(const float* __restrict__ accums, float* __restrict__ dout) {
  if (threadIdx.x == 0) {
    float rec = accums[0] / (float)((size_t)B_ * T_ * I_);
    float kl = -0.5f * accums[1];
    dout[(size_t)B_*T_*I_ + 2 * B_ * L_] = rec + kl;
  }
}

extern "C" void kernel_launch(void* const* d_in, const int* in_sizes, int n_in,
                              void* d_out, int out_size, void* d_ws, size_t ws_size,
                              hipStream_t stream) {
  const float* motion = (const float*)d_in[0];
  const float* eps    = (const float*)d_in[1];
  const float* eWih   = (const float*)d_in[2];
  const float* eWhh   = (const float*)d_in[3];
  const float* eb     = (const float*)d_in[4];
  const float* muW    = (const float*)d_in[5];
  const float* mub    = (const float*)d_in[6];
  const float* varW   = (const float*)d_in[7];
  const float* varb   = (const float*)d_in[8];
  const float* fcW    = (const float*)d_in[9];
  const float* fcb    = (const float*)d_in[10];
  const float* dWih   = (const float*)d_in[11];
  const float* dWhh   = (const float*)d_in[12];
  const float* db     = (const float*)d_in[13];
  const float* oW     = (const float*)d_in[14];
  const float* obv    = (const float*)d_in[15];
  float* out = (float*)d_out;

  // ws layout: [0,256)   accums
  //            [256, 256+131072)  dh0 (256x128 f32)
  //            [131328, +134217728)  XP f16 (B*T x 512)
  float* accums = (float*)d_ws;
  float* dh0    = (float*)((char*)d_ws + 256);
  const size_t xp_off = 256 + 131072;
  const size_t need = xp_off + (size_t)B_ * T_ * 512 * sizeof(half_t);
  const bool big = ws_size >= need;
  half_t* XP = (half_t*)((char*)d_ws + xp_off);

  hipLaunchKernelGGL(init_kernel, dim3(1), dim3(64), 0, stream, accums);
  if (big) {
    hipLaunchKernelGGL(xproj_kernel, dim3(2048), dim3(1024), 0, stream,
                       motion, eWih, eb, XP);
    hipLaunchKernelGGL(enc_rec_kernel, dim3(B_), dim3(1024), 0, stream,
                       XP, eps, eWhh, muW, mub, varW, varb, fcW, fcb,
                       out, dh0, accums);
  } else {
    hipLaunchKernelGGL(enc_fb_kernel, dim3(B_), dim3(1024), 0, stream,
                       motion, eps, eWih, eWhh, eb, muW, mub, varW, varb, fcW, fcb,
                       out, dh0, accums);
  }
  hipLaunchKernelGGL(dec_kernel, dim3(B_), dim3(1024), 0, stream,
                     motion, dWih, dWhh, db, oW, obv, dh0, out, accums);
  hipLaunchKernelGGL(fin_kernel, dim3(1), dim3(64), 0, stream, accums, out);
}